// Round 1
// baseline (88.573 us; speedup 1.0000x reference)
//
#include <hip/hip_runtime.h>
#include <hip/hip_bf16.h>

#define B_   4096
#define S_   32
#define IN_  256
#define H_   128
#define OUT_ 256

typedef __attribute__((ext_vector_type(8))) short bf16x8;
typedef __attribute__((ext_vector_type(4))) float f32x4;
typedef unsigned long long ull;

__device__ __forceinline__ unsigned short f2bf(float f) {
    union { float f; unsigned u; } v; v.f = f;
    unsigned r = v.u + 0x7FFFu + ((v.u >> 16) & 1u);   // round-to-nearest-even
    return (unsigned short)(r >> 16);
}

// Transpose + f32->bf16 convert: in [S][R][C] f32  ->  out [S][C][R] bf16
// grid.x = S * (R/32) * (C/32), block = 256
__global__ void transpose_cvt_kernel(const float* __restrict__ in,
                                     unsigned short* __restrict__ out,
                                     int R, int C) {
    __shared__ float tile[32][33];
    const int tilesR = R >> 5, tilesC = C >> 5;
    const int bid = blockIdx.x;
    const int s   = bid / (tilesR * tilesC);
    const int rem = bid % (tilesR * tilesC);
    const int tr  = rem / tilesC, tc = rem % tilesC;
    const float* ip = in + (size_t)s * R * C;
    unsigned short* op = out + (size_t)s * C * R;
    const int t  = threadIdx.x;
    const int c  = t & 31;
    const int r4 = t >> 5;            // 0..7
#pragma unroll
    for (int i = 0; i < 4; ++i) {
        int r = r4 * 4 + i;
        tile[r][c] = ip[(size_t)(tr * 32 + r) * C + tc * 32 + c];
    }
    __syncthreads();
#pragma unroll
    for (int i = 0; i < 4; ++i) {
        int orow = r4 * 4 + i;        // output row within tile (original col)
        int ocol = c;                 // output col within tile (original row)
        op[(size_t)(tc * 32 + orow) * R + tr * 32 + ocol] = f2bf(tile[ocol][orow]);
    }
}

// Fused per-subband MLP: out[b][s][:] = relu(x[b][s][:] @ W1[s] + b1[s]) @ W2[s] + b2[s]
// grid = S * (B/64), s-major. block = 256 (4 waves). BM = 64 rows per block.
__global__ __launch_bounds__(256) void subband_fused_kernel(
        const float* __restrict__ x,
        const unsigned short* __restrict__ w1t,   // [S][H][IN] bf16
        const float* __restrict__ b1,             // [S][H]
        const unsigned short* __restrict__ w2t,   // [S][OUT][H] bf16
        const float* __restrict__ b2,             // [S][OUT]
        float* __restrict__ out) {
    __shared__ __align__(16) unsigned char lds[49152];
    // xs: bytes [0, 32768):      [64 rows][512 B] (256 bf16/row), XOR-swizzled
    // hs: bytes [32768, 49152):  [64 rows][256 B] (128 bf16/row), XOR-swizzled
    unsigned char* xs = lds;
    unsigned char* hs = lds + 32768;

    const int bid  = blockIdx.x;
    const int s    = bid >> 6;          // 64 row-tiles per subband
    const int b0   = (bid & 63) << 6;   // first row of this tile
    const int tid  = threadIdx.x;
    const int lane = tid & 63;
    const int w    = tid >> 6;          // wave 0..3
    const int l15  = lane & 15;
    const int l4   = lane >> 4;         // 0..3

    // ---------- stage X tile (64 x 256 f32) -> xs as bf16, swizzled ----------
    {
        const int c4 = tid & 63;        // float4 column index 0..63
        const int rb = tid >> 6;        // row offset 0..3
#pragma unroll 4
        for (int it = 0; it < 16; ++it) {
            const int r = it * 4 + rb;
            const float4 v = *(const float4*)(x + ((size_t)(b0 + r) * S_ + s) * IN_ + (c4 << 2));
            ull p = (ull)f2bf(v.x) | ((ull)f2bf(v.y) << 16) |
                    ((ull)f2bf(v.z) << 32) | ((ull)f2bf(v.w) << 48);
            *(ull*)(xs + r * 512 + (((c4 << 3)) ^ ((r & 7) << 4))) = p;
        }
    }
    __syncthreads();

    // ---------- layer 1: H[64][128] = relu(X @ W1 + b1) ----------
    // wave w computes columns [w*32, w*32+32)
    f32x4 acc1[4][2] = {};
#pragma unroll
    for (int kk = 0; kk < 8; ++kk) {
        const int kb = kk * 32 + l4 * 8;       // k element offset for this lane
        bf16x8 a[4];
#pragma unroll
        for (int rt = 0; rt < 4; ++rt) {
            const int r = rt * 16 + l15;
            a[rt] = *(const bf16x8*)(xs + r * 512 + ((kb * 2) ^ ((r & 7) << 4)));
        }
        bf16x8 bb[2];
#pragma unroll
        for (int ct = 0; ct < 2; ++ct) {
            const int n = (w << 5) + ct * 16 + l15;
            bb[ct] = *(const bf16x8*)(w1t + (size_t)(s * H_ + n) * IN_ + kb);
        }
#pragma unroll
        for (int rt = 0; rt < 4; ++rt)
#pragma unroll
            for (int ct = 0; ct < 2; ++ct)
                acc1[rt][ct] = __builtin_amdgcn_mfma_f32_16x16x32_bf16(a[rt], bb[ct], acc1[rt][ct], 0, 0, 0);
    }
    // bias + relu -> hs (bf16, swizzled). C/D layout: col = l15, row = l4*4 + i.
    {
        float bias1[2];
        bias1[0] = b1[s * H_ + (w << 5) + l15];
        bias1[1] = b1[s * H_ + (w << 5) + 16 + l15];
#pragma unroll
        for (int rt = 0; rt < 4; ++rt)
#pragma unroll
            for (int ct = 0; ct < 2; ++ct)
#pragma unroll
                for (int i = 0; i < 4; ++i) {
                    float v = acc1[rt][ct][i] + bias1[ct];
                    v = fmaxf(v, 0.0f);
                    const int r = rt * 16 + l4 * 4 + i;
                    const int n = (w << 5) + ct * 16 + l15;
                    *(unsigned short*)(hs + r * 256 + ((n * 2) ^ ((r & 7) << 4))) = f2bf(v);
                }
    }
    __syncthreads();

    // ---------- layer 2: OUT[64][256] = H @ W2 + b2 ----------
    // wave w computes columns [w*64, w*64+64)
    f32x4 acc2[4][4] = {};
#pragma unroll
    for (int kk = 0; kk < 4; ++kk) {
        const int kb = kk * 32 + l4 * 8;
        bf16x8 a[4];
#pragma unroll
        for (int rt = 0; rt < 4; ++rt) {
            const int r = rt * 16 + l15;
            a[rt] = *(const bf16x8*)(hs + r * 256 + ((kb * 2) ^ ((r & 7) << 4)));
        }
        bf16x8 bb[4];
#pragma unroll
        for (int ct = 0; ct < 4; ++ct) {
            const int n = (w << 6) + ct * 16 + l15;
            bb[ct] = *(const bf16x8*)(w2t + (size_t)(s * OUT_ + n) * H_ + kb);
        }
#pragma unroll
        for (int rt = 0; rt < 4; ++rt)
#pragma unroll
            for (int ct = 0; ct < 4; ++ct)
                acc2[rt][ct] = __builtin_amdgcn_mfma_f32_16x16x32_bf16(a[rt], bb[ct], acc2[rt][ct], 0, 0, 0);
    }
    // bias + store f32
    {
        float bias2[4];
#pragma unroll
        for (int ct = 0; ct < 4; ++ct)
            bias2[ct] = b2[s * OUT_ + (w << 6) + ct * 16 + l15];
#pragma unroll
        for (int rt = 0; rt < 4; ++rt)
#pragma unroll
            for (int ct = 0; ct < 4; ++ct)
#pragma unroll
                for (int i = 0; i < 4; ++i) {
                    const int r = b0 + rt * 16 + l4 * 4 + i;
                    const int n = (w << 6) + ct * 16 + l15;
                    out[((size_t)r * S_ + s) * OUT_ + n] = acc2[rt][ct][i] + bias2[ct];
                }
    }
}

extern "C" void kernel_launch(void* const* d_in, const int* in_sizes, int n_in,
                              void* d_out, int out_size, void* d_ws, size_t ws_size,
                              hipStream_t stream) {
    const float* x  = (const float*)d_in[0];
    const float* W1 = (const float*)d_in[1];
    const float* b1 = (const float*)d_in[2];
    const float* W2 = (const float*)d_in[3];
    const float* b2 = (const float*)d_in[4];
    float* out = (float*)d_out;

    unsigned short* w1t = (unsigned short*)d_ws;                 // [S][H][IN]  bf16: 2 MiB
    unsigned short* w2t = w1t + (size_t)S_ * H_ * IN_;           // [S][OUT][H] bf16: 2 MiB

    transpose_cvt_kernel<<<S_ * (IN_ / 32) * (H_ / 32), 256, 0, stream>>>(W1, w1t, IN_, H_);
    transpose_cvt_kernel<<<S_ * (H_ / 32) * (OUT_ / 32), 256, 0, stream>>>(W2, w2t, H_, OUT_);
    subband_fused_kernel<<<S_ * (B_ / 64), 256, 0, stream>>>(x, w1t, b1, w2t, b2, out);
}